// Round 5
// baseline (346.273 us; speedup 1.0000x reference)
//
#include <hip/hip_runtime.h>
#include <hip/hip_fp16.h>

// ComplexFaberConv: degree-normalized directed SpMM + collapsed complex linear.
//
// Math (linear in k, so W-stacks collapse):
//   WrE = sum_k 0.5^k W_real[k], WiE likewise; brE, biE likewise.
//   u = y_real, v = y_real_t, S = y_imag + y_imag_t
//   total_real = 0.5*(u+v)@WrE^T - 0.5*S@WiE^T + (brE-biE)
//   total_imag = u@WiE^T + 0.5*S@WrE^T + (brE+biE)
// (reference faithfully uses y_real, not y_real_t, in sum_imag_d2s)
//
// R7: MFMA gemm epilogue in its own dispatch (gather 211 -> 124 us).
// R8: single unscaled xp array, per-edge inv scale packed in idx bits
//     (gather 124 -> 113 us; L2-churn-limited, structural).
// R9 FAILED: fusing gemm into gather tanked occupancy/MLP.
// R10 NEUTRAL: 14 -> 9 dispatches saved only 2 us -> launch gaps / pass count
//     were never the cost.
// R11 (this round): the ~200 us build chain is LATENCY-bound: 1-1.5 blocks/CU
// and serial {4B load -> LDS atomic} chains expose full memory latency per
// iteration. Fixes: int4 edge loads (4 independent chains/iter), 4-way
// stride-256 unrolls in the bucket kernels, 1024-block grid-stride count,
// 64B-strided global atomic counters (no cross-XCD line ping-pong), gemm grid
// 512 -> 1568. Hot gather/gemm logic unchanged.

constexpr int D = 64;
constexpr int GSC = 500;  // part_scatter blocks: E=1.6M -> CH=3200 (divisible by 4)

typedef _Float16 f16x8 __attribute__((ext_vector_type(8)));
typedef float f32x4 __attribute__((ext_vector_type(4)));

__device__ __forceinline__ float2 h2_to_f2(uint p) {
  __half2 h = *(__half2*)&p;
  return __half22float2(h);
}

// ---------- partition phase ----------

// Grid-strided int4 histogram of buckets -> strided global totals.
// Tcnt[(dir*NBUK+b)<<4]; bucket = node>>9.
__global__ __launch_bounds__(256) void part_count(
    const int* __restrict__ row, const int* __restrict__ col,
    int* __restrict__ Tcnt, int E, int NBUK) {
  __shared__ int ho[256], hi_[256];
  int t = threadIdx.x;
  ho[t] = 0;
  hi_[t] = 0;
  __syncthreads();
  int E4 = E >> 2;
  int stride = gridDim.x * 256;
  for (int gi = blockIdx.x * 256 + t; gi < E4; gi += stride) {
    int4 r4 = ((const int4*)row)[gi];
    int4 c4 = ((const int4*)col)[gi];
    atomicAdd(&ho[r4.x >> 9], 1);
    atomicAdd(&ho[r4.y >> 9], 1);
    atomicAdd(&ho[r4.z >> 9], 1);
    atomicAdd(&ho[r4.w >> 9], 1);
    atomicAdd(&hi_[c4.x >> 9], 1);
    atomicAdd(&hi_[c4.y >> 9], 1);
    atomicAdd(&hi_[c4.z >> 9], 1);
    atomicAdd(&hi_[c4.w >> 9], 1);
  }
  if (blockIdx.x == 0 && t < (E & 3)) {  // tail edges (none when E%4==0)
    int e = (E & ~3) + t;
    atomicAdd(&ho[row[e] >> 9], 1);
    atomicAdd(&hi_[col[e] >> 9], 1);
  }
  __syncthreads();
  if (t < NBUK) {
    if (ho[t]) atomicAdd(&Tcnt[t << 4], ho[t]);
    if (hi_[t]) atomicAdd(&Tcnt[(NBUK + t) << 4], hi_[t]);
  }
}

// Fused prep: (a) 196-entry exclusive scan of bucket totals -> bases Bb_* and
// strided atomic cursors Ccur; (b) collapse K=3 weight stacks (LDS Wh) and
// emit MFMA B-fragments + collapsed biases.
//   Bfrag[fr][lane] = 8 f16, fr = ((mat*4+kt)*4+nt), element:
//     k_local = 8*(lane>>4) + j + 32*kt  (0..127),  o = (lane&15) + 16*nt
//     mat 0 (real): k<64 -> wr[k][o], else -wi[k-64][o]
//     mat 1 (imag): k<64 -> wr[k][o], else +wi[k-64][o]
__global__ __launch_bounds__(1024) void prep_kernel(
    const float* __restrict__ Wr, const float* __restrict__ br,
    const float* __restrict__ Wi, const float* __restrict__ bi,
    const int* __restrict__ Tcnt, uint4* __restrict__ Bfrag,
    float* __restrict__ cR, float* __restrict__ cI,
    int* __restrict__ Bb_out, int* __restrict__ Bb_in, int* __restrict__ Ccur,
    int E, int NBUK) {
  __shared__ uint sWh[4096];  // Wh[d*64+o]
  __shared__ int ws[8];
  int t = threadIdx.x;
  for (int i = t; i < 4096; i += 1024) {
    int o = i >> 6, d = i & 63;
    float wr = Wr[i] + 0.5f * Wr[4096 + i] + 0.25f * Wr[8192 + i];
    float wi = Wi[i] + 0.5f * Wi[4096 + i] + 0.25f * Wi[8192 + i];
    __half2 h = __floats2half2_rn(wr, wi);
    sWh[d * 64 + o] = *(uint*)&h;
  }
  if (t < 64) {
    float brv = br[t] + 0.5f * br[64 + t] + 0.25f * br[128 + t];
    float biv = bi[t] + 0.5f * bi[64 + t] + 0.25f * bi[128 + t];
    cR[t] = brv - biv;
    cI[t] = brv + biv;
  }
  // scan of bucket totals: threads 0..511, dir = t>>8 (waves 0..3 / 4..7)
  int dir = 0, tl = 0, v = 0, sc = 0;
  int lane = t & 63, wv = t >> 6;
  if (t < 512) {
    dir = t >> 8;
    tl = t & 255;
    v = (tl < NBUK) ? Tcnt[(dir * NBUK + tl) << 4] : 0;
    sc = v;
#pragma unroll
    for (int off = 1; off < 64; off <<= 1) {
      int u = __shfl_up(sc, off);
      if (lane >= off) sc += u;
    }
    if (lane == 63) ws[wv] = sc;
  }
  __syncthreads();
  if (t < 512) {
    int wbase = 0;
#pragma unroll
    for (int w = 0; w < 8; ++w)
      if (w >= (dir << 2) && w < wv) wbase += ws[w];
    int excl = wbase + sc - v;
    int* Bb = dir ? Bb_in : Bb_out;
    if (tl < NBUK) {
      Bb[tl] = excl;
      Ccur[(dir * NBUK + tl) << 4] = excl;
      if (tl == NBUK - 1) Bb[NBUK] = excl + v;  // == E
    }
  }
  // B-fragment emit (sWh ready after the sync above)
  for (int tt = t; tt < 2048; tt += 1024) {
    int ln = tt & 63, fr = tt >> 6;
    int mat = fr >> 4, kt = (fr >> 2) & 3, nt = fr & 3;
    int o = (ln & 15) + 16 * nt;
    int k0 = 8 * (ln >> 4) + 32 * kt;
    uint wbits[4];
#pragma unroll
    for (int jj = 0; jj < 4; ++jj) {
      float vv[2];
#pragma unroll
      for (int s = 0; s < 2; ++s) {
        int k = k0 + 2 * jj + s;
        float2 wrwi = h2_to_f2(sWh[(k & 63) * 64 + o]);
        vv[s] = (k < 64) ? wrwi.x : (mat ? wrwi.y : -wrwi.y);
      }
      __half2 hh = __floats2half2_rn(vv[0], vv[1]);
      wbits[jj] = *(uint*)&hh;
    }
    Bfrag[tt] = make_uint4(wbits[0], wbits[1], wbits[2], wbits[3]);
  }
}

// Scatter edges into bucket-contiguous regions. Each block counts its chunk
// (int4 loads, LDS histogram), reserves a range per bucket via ONE strided
// global atomicAdd, then scatters with 4 independent chains per iteration.
// pack = (node_local<<17) | neighbor.
__global__ __launch_bounds__(256) void part_scatter(
    const int* __restrict__ row, const int* __restrict__ col,
    int* __restrict__ Ccur,
    uint* __restrict__ pout, uint* __restrict__ pin, int E, int NBUK, int CH) {
  __shared__ int co[256], ci[256];
  int t = threadIdx.x, g = blockIdx.x;
  co[t] = 0;
  ci[t] = 0;
  __syncthreads();
  int e0 = g * CH, e1 = min(E, e0 + CH);
  int g0 = e0 >> 2, g1 = (e1 + 3) >> 2;  // CH%4==0 -> exact int4 groups
  for (int gi = g0 + t; gi < g1; gi += 256) {
    int4 r4 = ((const int4*)row)[gi];
    int4 c4 = ((const int4*)col)[gi];
    atomicAdd(&co[r4.x >> 9], 1);
    atomicAdd(&co[r4.y >> 9], 1);
    atomicAdd(&co[r4.z >> 9], 1);
    atomicAdd(&co[r4.w >> 9], 1);
    atomicAdd(&ci[c4.x >> 9], 1);
    atomicAdd(&ci[c4.y >> 9], 1);
    atomicAdd(&ci[c4.z >> 9], 1);
    atomicAdd(&ci[c4.w >> 9], 1);
  }
  __syncthreads();
  if (t < NBUK) {
    int c = co[t];
    co[t] = c ? atomicAdd(&Ccur[t << 4], c) : 0;
    c = ci[t];
    ci[t] = c ? atomicAdd(&Ccur[(NBUK + t) << 4], c) : 0;
  }
  __syncthreads();
  for (int gi = g0 + t; gi < g1; gi += 256) {
    int4 r4 = ((const int4*)row)[gi];
    int4 c4 = ((const int4*)col)[gi];
#define SCAT1(R, C)                                          \
  {                                                          \
    int po = atomicAdd(&co[(R) >> 9], 1);                    \
    pout[po] = ((uint)((R) & 511) << 17) | (uint)(C);        \
    int pi = atomicAdd(&ci[(C) >> 9], 1);                    \
    pin[pi] = ((uint)((C) & 511) << 17) | (uint)(R);         \
  }
    SCAT1(r4.x, c4.x);
    SCAT1(r4.y, c4.y);
    SCAT1(r4.z, c4.z);
    SCAT1(r4.w, c4.w);
#undef SCAT1
  }
}

// One block per (bucket,dir): LDS degree histogram (4-way unrolled loads) +
// LOCAL 512-element exclusive scan -> ofs (= bucket_base + local_prefix) and
// inv = deg^-0.25.
__global__ __launch_bounds__(256) void offsets_kernel(
    const uint* __restrict__ pout, const uint* __restrict__ pin,
    const int* __restrict__ Bb_out, const int* __restrict__ Bb_in,
    int* __restrict__ ofs_out, int* __restrict__ ofs_in,
    float* __restrict__ inv_out, float* __restrict__ inv_in,
    int E, int NBUK, int N) {
  const uint* p = blockIdx.y ? pin : pout;
  const int* Bb = blockIdx.y ? Bb_in : Bb_out;
  int* ofs = blockIdx.y ? ofs_in : ofs_out;
  float* inv = blockIdx.y ? inv_in : inv_out;
  __shared__ int ld[512];
  __shared__ int ws[4];
  int t = threadIdx.x, b = blockIdx.x;
  ld[t] = 0;
  ld[t + 256] = 0;
  __syncthreads();
  int win_s = Bb[b], win_e = Bb[b + 1];
  int j = win_s + t;
  for (; j + 768 < win_e; j += 1024) {
    uint p0 = p[j], p1 = p[j + 256], p2 = p[j + 512], p3 = p[j + 768];
    atomicAdd(&ld[p0 >> 17], 1);
    atomicAdd(&ld[p1 >> 17], 1);
    atomicAdd(&ld[p2 >> 17], 1);
    atomicAdd(&ld[p3 >> 17], 1);
  }
  for (; j < win_e; j += 256) atomicAdd(&ld[p[j] >> 17], 1);
  __syncthreads();
  int a0 = ld[2 * t], a1 = ld[2 * t + 1], sm = a0 + a1;
  int lane = t & 63, wv = t >> 6, sc = sm;
#pragma unroll
  for (int off = 1; off < 64; off <<= 1) {
    int u = __shfl_up(sc, off);
    if (lane >= off) sc += u;
  }
  if (lane == 63) ws[wv] = sc;
  __syncthreads();
  int wbase = 0;
#pragma unroll
  for (int w = 0; w < 4; ++w)
    if (w < wv) wbase += ws[w];
  int excl = wbase + sc - sm;
  int n0 = (b << 9) + 2 * t;
  if (n0 < N) {
    ofs[n0] = win_s + excl;
    inv[n0] = a0 ? rsqrtf(sqrtf((float)a0)) : 0.0f;
  }
  if (n0 + 1 < N) {
    ofs[n0 + 1] = win_s + excl + a0;
    inv[n0 + 1] = a1 ? rsqrtf(sqrtf((float)a1)) : 0.0f;
  }
  if (b == 0 && t == 0) ofs[N] = E;
}

// One block per (bucket,dir): LDS cursors seeded from ofs; 4-way unrolled fill.
// idx entry = (f16bits(inv_of_neighbor)<<17) | neighbor. y=0: pout->idx_out,
// neighbors are cols -> inv_in; y=1: pin->idx_in, neighbors are rows -> inv_out.
__global__ __launch_bounds__(256) void bucket_fill(
    const uint* __restrict__ pout, const uint* __restrict__ pin,
    const int* __restrict__ Bb_out, const int* __restrict__ Bb_in,
    const int* __restrict__ ofs_out, const int* __restrict__ ofs_in,
    const float* __restrict__ inv_out, const float* __restrict__ inv_in,
    uint* __restrict__ idx_out, uint* __restrict__ idx_in, int E, int NBUK, int N) {
  const uint* p = blockIdx.y ? pin : pout;
  const int* Bb = blockIdx.y ? Bb_in : Bb_out;
  const int* ofs = blockIdx.y ? ofs_in : ofs_out;
  const float* invnb = blockIdx.y ? inv_out : inv_in;
  uint* idx = blockIdx.y ? idx_in : idx_out;
  __shared__ int cur[512];
  int t = threadIdx.x, b = blockIdx.x;
  int n0 = (b << 9) + t;
  cur[t] = (n0 < N) ? ofs[n0] : 0;
  cur[t + 256] = (n0 + 256 < N) ? ofs[n0 + 256] : 0;
  __syncthreads();
  int s = Bb[b], e = Bb[b + 1];
#define FILL1(PK)                                                       \
  {                                                                     \
    uint nbr = (PK) & 0x1FFFFu;                                         \
    uint hb = (uint)__half_as_ushort(__float2half(invnb[nbr]));         \
    int pos = atomicAdd(&cur[(PK) >> 17], 1);                           \
    idx[pos] = (hb << 17) | nbr;                                        \
  }
  int j = s + t;
  for (; j + 768 < e; j += 1024) {
    uint p0 = p[j], p1 = p[j + 256], p2 = p[j + 512], p3 = p[j + 768];
    FILL1(p0);
    FILL1(p1);
    FILL1(p2);
    FILL1(p3);
  }
  for (; j < e; j += 256) {
    uint pk = p[j];
    FILL1(pk);
  }
#undef FILL1
}

// ---------- dense prep ----------

// Unscaled packed features: xp[n*64+d] = half2(xr, xi). 25.6 MB, single array
// for both gather directions (scale rides in the idx entries).
__global__ void pack_kernel(const float* __restrict__ xr, const float* __restrict__ xi,
                            uint* __restrict__ xp, int total4) {
  int i = blockIdx.x * blockDim.x + threadIdx.x;  // over N*16 uint4 groups
  if (i < total4) {
    float4 a = ((const float4*)xr)[i];
    float4 b = ((const float4*)xi)[i];
    __half2 h;
    uint4 o;
    h = __floats2half2_rn(a.x, b.x); o.x = *(uint*)&h;
    h = __floats2half2_rn(a.y, b.y); o.y = *(uint*)&h;
    h = __floats2half2_rn(a.z, b.z); o.z = *(uint*)&h;
    h = __floats2half2_rn(a.w, b.w); o.w = *(uint*)&h;
    ((uint4*)xp)[i] = o;
  }
}

// ---------- sparse gather (R8 form, verbatim) ----------
// One wave per node. Lane l handles features 4*(l&15)..+3 of edge j+(l>>4):
// one dwordx4 gather covers 4 edges per wave-instruction; unroll 2.
// idx entry = (f16bits(inv_nbr)<<17)|nbr; accumulate via fma with decoded scale.
// Output: Apack[n][k], k in [0,192) f16: [p(64) | sh(64) | u(64)], written by
// the sub==0 quarter-wave. No LDS (epilogue lives in gemm_kernel).
__global__ __launch_bounds__(256) void gather_kernel(
    const uint4* __restrict__ xp4,
    const uint* __restrict__ idx_out, const uint* __restrict__ idx_in,
    const int* __restrict__ ofs_out, const int* __restrict__ ofs_in,
    const float* __restrict__ inv_out, const float* __restrict__ inv_in,
    uint* __restrict__ Apack, int N) {
  int wv = threadIdx.x >> 6;
  int lane = threadIdx.x & 63;
  int sub = lane >> 4;  // edge slot 0..3
  int q = lane & 15;    // uint4 slot -> features 4q..4q+3
  int wid = blockIdx.x * 4 + wv;
  int nw = gridDim.x * 4;
  for (int n = wid; n < N; n += nw) {
    float4 u1 = {0, 0, 0, 0}, s1 = {0, 0, 0, 0};
    float4 v2 = {0, 0, 0, 0}, s2 = {0, 0, 0, 0};
#define ACC(P, SC, U, S)                                                \
  {                                                                     \
    float2 a0 = h2_to_f2((P).x), a1 = h2_to_f2((P).y);                  \
    float2 a2 = h2_to_f2((P).z), a3 = h2_to_f2((P).w);                  \
    U.x += SC * a0.x; S.x += SC * a0.y; U.y += SC * a1.x; S.y += SC * a1.y; \
    U.z += SC * a2.x; S.z += SC * a2.y; U.w += SC * a3.x; S.w += SC * a3.y; \
  }
#define DEC(E) __half2float(__ushort_as_half((ushort)((E) >> 17)))
    {  // out-direction: neighbors scaled by inv_in[nbr] (in idx bits)
      int lo = ofs_out[n], hi = ofs_out[n + 1];
      int len8 = (hi - lo) & ~7;
      int j = lo;
      for (; j < lo + len8; j += 8) {
        uint e0 = idx_out[j + sub];
        uint e1 = idx_out[j + 4 + sub];
        uint4 p0 = xp4[(size_t)(e0 & 0x1FFFFu) * 16 + q];
        uint4 p1 = xp4[(size_t)(e1 & 0x1FFFFu) * 16 + q];
        float sc0 = DEC(e0), sc1 = DEC(e1);
        ACC(p0, sc0, u1, s1);
        ACC(p1, sc1, u1, s1);
      }
      for (; j < hi; j += 4) {
        if (j + sub < hi) {
          uint e0 = idx_out[j + sub];
          uint4 p0 = xp4[(size_t)(e0 & 0x1FFFFu) * 16 + q];
          float sc0 = DEC(e0);
          ACC(p0, sc0, u1, s1);
        }
      }
    }
    {  // in-direction: neighbors scaled by inv_out[nbr] (in idx bits)
      int lo = ofs_in[n], hi = ofs_in[n + 1];
      int len8 = (hi - lo) & ~7;
      int j = lo;
      for (; j < lo + len8; j += 8) {
        uint e0 = idx_in[j + sub];
        uint e1 = idx_in[j + 4 + sub];
        uint4 p0 = xp4[(size_t)(e0 & 0x1FFFFu) * 16 + q];
        uint4 p1 = xp4[(size_t)(e1 & 0x1FFFFu) * 16 + q];
        float sc0 = DEC(e0), sc1 = DEC(e1);
        ACC(p0, sc0, v2, s2);
        ACC(p1, sc1, v2, s2);
      }
      for (; j < hi; j += 4) {
        if (j + sub < hi) {
          uint e0 = idx_in[j + sub];
          uint4 p0 = xp4[(size_t)(e0 & 0x1FFFFu) * 16 + q];
          float sc0 = DEC(e0);
          ACC(p0, sc0, v2, s2);
        }
      }
    }
#undef ACC
#undef DEC
    // reduce the 4 edge-subgroups (lanes l, l^16, l^32, l^48)
#pragma unroll
    for (int m = 16; m < 64; m <<= 1) {
      u1.x += __shfl_xor(u1.x, m); u1.y += __shfl_xor(u1.y, m);
      u1.z += __shfl_xor(u1.z, m); u1.w += __shfl_xor(u1.w, m);
      s1.x += __shfl_xor(s1.x, m); s1.y += __shfl_xor(s1.y, m);
      s1.z += __shfl_xor(s1.z, m); s1.w += __shfl_xor(s1.w, m);
      v2.x += __shfl_xor(v2.x, m); v2.y += __shfl_xor(v2.y, m);
      v2.z += __shfl_xor(v2.z, m); v2.w += __shfl_xor(v2.w, m);
      s2.x += __shfl_xor(s2.x, m); s2.y += __shfl_xor(s2.y, m);
      s2.z += __shfl_xor(s2.z, m); s2.w += __shfl_xor(s2.w, m);
    }
    if (sub == 0) {  // lanes 0..15 hold features 4q..4q+3
      float io = inv_out[n], ii = inv_in[n];
      float4 uu = make_float4(io * u1.x, io * u1.y, io * u1.z, io * u1.w);
      float4 vv = make_float4(ii * v2.x, ii * v2.y, ii * v2.z, ii * v2.w);
      float4 ss = make_float4(io * s1.x + ii * s2.x, io * s1.y + ii * s2.y,
                              io * s1.z + ii * s2.z, io * s1.w + ii * s2.w);
      uint* base = Apack + (size_t)n * 96 + 2 * q;  // row = 192 f16 = 96 uints
      __half2 h;
      uint2 w;
      h = __floats2half2_rn(0.5f * (uu.x + vv.x), 0.5f * (uu.y + vv.y)); w.x = *(uint*)&h;
      h = __floats2half2_rn(0.5f * (uu.z + vv.z), 0.5f * (uu.w + vv.w)); w.y = *(uint*)&h;
      *(uint2*)base = w;  // p
      h = __floats2half2_rn(0.5f * ss.x, 0.5f * ss.y); w.x = *(uint*)&h;
      h = __floats2half2_rn(0.5f * ss.z, 0.5f * ss.w); w.y = *(uint*)&h;
      *(uint2*)(base + 32) = w;  // sh
      h = __floats2half2_rn(uu.x, uu.y); w.x = *(uint*)&h;
      h = __floats2half2_rn(uu.z, uu.w); w.y = *(uint*)&h;
      *(uint2*)(base + 64) = w;  // u
    }
  }
}

// ---------- dense epilogue: tall-skinny MFMA GEMM (R8 form; grid widened) ----------
// Per wave per 16-node tile: 6 A-frags (k windows of 32), 32 mfma_f32_16x16x32_f16.
//   real: C[n][o]   = sum_{kt=0..3} A(kt)   * Breal(kt)   (k in [0,128))
//   imag: C[n][o]   = sum_{kt=0..3} A(kt+2) * Bimag(kt)   (k in [64,192))
// A-frag: row = lane&15, k = 8*(lane>>4)+j. B-frag: col = lane&15, same k.
// C/D: col = lane&15, row = 4*(lane>>4)+reg  [m89-verified layout].
__global__ __launch_bounds__(256) void gemm_kernel(
    const ushort* __restrict__ Apack, const uint4* __restrict__ Bfrag,
    const float* __restrict__ cR, const float* __restrict__ cI,
    float* __restrict__ out_real, float* __restrict__ out_imag, int N) {
  __shared__ uint4 sB[2048];  // 32 KB: [fr(32)][lane(64)]
  for (int i = threadIdx.x; i < 2048; i += 256) sB[i] = Bfrag[i];
  __syncthreads();
  int lane = threadIdx.x & 63, wv = threadIdx.x >> 6;
  int l15 = lane & 15, l4 = lane >> 4;
  float bR[4], bI[4];
#pragma unroll
  for (int nt = 0; nt < 4; ++nt) {
    bR[nt] = cR[l15 + 16 * nt];
    bI[nt] = cI[l15 + 16 * nt];
  }
  int tiles = (N + 15) >> 4;
  int gw = blockIdx.x * 4 + wv, nw = gridDim.x * 4;
  for (int tt = gw; tt < tiles; tt += nw) {
    int n0 = tt << 4;
    int arow = min(n0 + l15, N - 1);
    const ushort* ap = Apack + (size_t)arow * 192 + 8 * l4;
    f16x8 a[6];
#pragma unroll
    for (int kt = 0; kt < 6; ++kt) a[kt] = *(const f16x8*)(ap + 32 * kt);
    f32x4 cr[4], ci[4];
#pragma unroll
    for (int nt = 0; nt < 4; ++nt) {
      cr[nt] = (f32x4){0.f, 0.f, 0.f, 0.f};
      ci[nt] = (f32x4){0.f, 0.f, 0.f, 0.f};
    }
#pragma unroll
    for (int kt = 0; kt < 4; ++kt) {
#pragma unroll
      for (int nt = 0; nt < 4; ++nt) {
        f16x8 b0 = *(const f16x8*)&sB[(kt * 4 + nt) * 64 + lane];
        cr[nt] = __builtin_amdgcn_mfma_f32_16x16x32_f16(a[kt], b0, cr[nt], 0, 0, 0);
        f16x8 b1 = *(const f16x8*)&sB[(16 + kt * 4 + nt) * 64 + lane];
        ci[nt] = __builtin_amdgcn_mfma_f32_16x16x32_f16(a[kt + 2], b1, ci[nt], 0, 0, 0);
      }
    }
#pragma unroll
    for (int nt = 0; nt < 4; ++nt) {
#pragma unroll
      for (int r = 0; r < 4; ++r) {
        int node = n0 + 4 * l4 + r;
        if (node < N) {
          out_real[(size_t)node * 64 + l15 + 16 * nt] = cr[nt][r] + bR[nt];
          out_imag[(size_t)node * 64 + l15 + 16 * nt] = ci[nt][r] + bI[nt];
        }
      }
    }
  }
}

extern "C" void kernel_launch(void* const* d_in, const int* in_sizes, int n_in,
                              void* d_out, int out_size, void* d_ws, size_t ws_size,
                              hipStream_t stream) {
  const float* x_real = (const float*)d_in[0];
  const float* x_imag = (const float*)d_in[1];
  const int* edge = (const int*)d_in[2];
  const float* W_real = (const float*)d_in[3];
  const float* b_real = (const float*)d_in[4];
  const float* W_imag = (const float*)d_in[5];
  const float* b_imag = (const float*)d_in[6];

  const int N = in_sizes[0] / D;  // 100000
  const int E = in_sizes[2] / 2;  // 1600000
  const int* row = edge;
  const int* col = edge + E;

  const int NBUK = (N + 511) >> 9;            // 196 buckets of 512 nodes
  const int CH = ((E / GSC + 3) & ~3);        // edges per scatter block (mult of 4)

  // workspace layout (16B-aligned packed arrays first).
  // Apack (N*96 uints) aliases pout/pin: pout/pin die after bucket_fill,
  // Apack is written by gather_kernel afterwards (2E = 3.2M < N*96 = 9.6M).
  uint* xp       = (uint*)d_ws;                    // N*64 (unscaled half2 pack)
  uint* idx_out  = xp + (size_t)N * D;             // E
  uint* idx_in   = idx_out + E;                    // E
  uint* Apack    = idx_in + E;                     // N*96  (f16 [N][192])
  uint* pout     = Apack;                          // E   (aliased, dead early)
  uint* pin      = pout + E;                       // E   (aliased, dead early)
  uint4* Bfrag   = (uint4*)(Apack + (size_t)N * 96);  // 2048 uint4 = 32 KB
  int* Tcnt      = (int*)(Bfrag + 2048);           // 2*NBUK*16 (64B-strided totals)
  int* Ccur      = Tcnt + 2 * NBUK * 16;           // 2*NBUK*16 (strided cursors)
  int* Bb_out    = Ccur + 2 * NBUK * 16;           // NBUK+1
  int* Bb_in     = Bb_out + NBUK + 1;              // NBUK+1
  int* ofs_out   = Bb_in + NBUK + 1;               // N+1
  int* ofs_in    = ofs_out + N + 1;                // N+1
  float* inv_out = (float*)(ofs_in + N + 1);       // N
  float* inv_in  = inv_out + N;                    // N
  float* cR      = inv_in + N;                     // 64
  float* cI      = cR + 64;                        // 64

  float* out_real = (float*)d_out;
  float* out_imag = out_real + (size_t)N * D;

  // zero the strided atomic bucket totals, then count (grid-strided, int4)
  hipMemsetAsync(Tcnt, 0, 2 * NBUK * 16 * sizeof(int), stream);
  part_count<<<1024, 256, 0, stream>>>(row, col, Tcnt, E, NBUK);

  // fused: bucket-base scan + cursor seed + weight collapse + B-fragments
  prep_kernel<<<1, 1024, 0, stream>>>(W_real, b_real, W_imag, b_imag, Tcnt,
                                      Bfrag, cR, cI, Bb_out, Bb_in, Ccur, E, NBUK);

  // unscaled feature pack (independent of the edge chain)
  pack_kernel<<<(N * 16 + 255) / 256, 256, 0, stream>>>(x_real, x_imag, xp, N * 16);

  // scatter edges into bucket regions (atomic range reservation, int4 loads)
  part_scatter<<<GSC, 256, 0, stream>>>(row, col, Ccur, pout, pin, E, NBUK, CH);

  // per-bucket degrees -> ofs/inv via local scan (4-way unrolled)
  offsets_kernel<<<dim3(NBUK, 2), 256, 0, stream>>>(pout, pin, Bb_out, Bb_in,
                                                    ofs_out, ofs_in, inv_out, inv_in,
                                                    E, NBUK, N);

  // per-bucket CSR fill (block-private windows; packs inv scale into idx)
  bucket_fill<<<dim3(NBUK, 2), 256, 0, stream>>>(pout, pin, Bb_out, Bb_in,
                                                 ofs_out, ofs_in, inv_out, inv_in,
                                                 idx_out, idx_in, E, NBUK, N);

  // sparse gather -> Apack (overwrites pout/pin, now dead)
  gather_kernel<<<4096, 256, 0, stream>>>((const uint4*)xp, idx_out, idx_in,
                                          ofs_out, ofs_in, inv_out, inv_in, Apack, N);
  // dense epilogue: MFMA GEMM
  gemm_kernel<<<1568, 256, 0, stream>>>((const ushort*)Apack, Bfrag, cR, cI,
                                        out_real, out_imag, N);
}

// Round 6
// 324.963 us; speedup vs baseline: 1.0656x; 1.0656x over previous
//
#include <hip/hip_runtime.h>
#include <hip/hip_fp16.h>

// ComplexFaberConv: degree-normalized directed SpMM + collapsed complex linear.
//
// Math (linear in k, so W-stacks collapse):
//   WrE = sum_k 0.5^k W_real[k], WiE likewise; brE, biE likewise.
//   u = y_real, v = y_real_t, S = y_imag + y_imag_t
//   total_real = 0.5*(u+v)@WrE^T - 0.5*S@WiE^T + (brE-biE)
//   total_imag = u@WiE^T + 0.5*S@WrE^T + (brE+biE)
// (reference faithfully uses y_real, not y_real_t, in sum_imag_d2s)
//
// R7: MFMA gemm epilogue in its own dispatch (gather 211 -> 124 us).
// R8: single unscaled xp array, per-edge inv scale packed in idx bits
//     (gather 124 -> 113 us; L2-churn-limited, structural).
// R9 FAILED: fusing gemm into gather tanked occupancy/MLP.
// R10/R11 NEUTRAL: dispatch-count and ILP weren't the cost; traffic audit
//     showed R10's pass removal was offset by part_scatter's added count pass.
// R12 (this round): FIXED-SIZE bucket slots (SLOTSZ=16384, ~2x max expected
// bucket load) delete part_count + memset entirely: cursors seed to b*SLOTSZ
// in prep; part_scatter reserves ranges as before; pout/pin and idx_* are
// slot-padded. Per-node ranges become int2 {start,end} pairs (bucket-local
// offsets aren't a global prefix; also halves gather's range loads).
// Chain: 10 GPU ops -> 7, -12.8 MB edge traffic. Hot gather/gemm verbatim.

constexpr int D = 64;
constexpr int GSC = 500;       // part_scatter blocks: E=1.6M -> CH=3200 (mult of 4)
constexpr int SLOTSZ = 16384;  // per-bucket slot (mean load 8163, max ~8.6K)

typedef _Float16 f16x8 __attribute__((ext_vector_type(8)));
typedef float f32x4 __attribute__((ext_vector_type(4)));

__device__ __forceinline__ float2 h2_to_f2(uint p) {
  __half2 h = *(__half2*)&p;
  return __half22float2(h);
}

// ---------- prep: weights + B-fragments + cursor seed ----------
// Bfrag[fr][lane] = 8 f16, fr = ((mat*4+kt)*4+nt), element:
//   k_local = 8*(lane>>4) + j + 32*kt  (0..127),  o = (lane&15) + 16*nt
//   mat 0 (real): k<64 -> wr[k][o], else -wi[k-64][o]
//   mat 1 (imag): k<64 -> wr[k][o], else +wi[k-64][o]
// Ccur[(dir*NBUK+b)<<4] = b*SLOTSZ (64B-strided atomic cursors).
__global__ __launch_bounds__(1024) void prep_kernel(
    const float* __restrict__ Wr, const float* __restrict__ br,
    const float* __restrict__ Wi, const float* __restrict__ bi,
    uint4* __restrict__ Bfrag, float* __restrict__ cR, float* __restrict__ cI,
    int* __restrict__ Ccur, int NBUK) {
  __shared__ uint sWh[4096];  // Wh[d*64+o]
  int t = threadIdx.x;
  for (int i = t; i < 4096; i += 1024) {
    int o = i >> 6, d = i & 63;
    float wr = Wr[i] + 0.5f * Wr[4096 + i] + 0.25f * Wr[8192 + i];
    float wi = Wi[i] + 0.5f * Wi[4096 + i] + 0.25f * Wi[8192 + i];
    __half2 h = __floats2half2_rn(wr, wi);
    sWh[d * 64 + o] = *(uint*)&h;
  }
  if (t < 64) {
    float brv = br[t] + 0.5f * br[64 + t] + 0.25f * br[128 + t];
    float biv = bi[t] + 0.5f * bi[64 + t] + 0.25f * bi[128 + t];
    cR[t] = brv - biv;
    cI[t] = brv + biv;
  }
  // seed strided cursors for both directions
  for (int i = t; i < 2 * NBUK; i += 1024) Ccur[i << 4] = (i % NBUK) * SLOTSZ;
  __syncthreads();
  for (int tt = t; tt < 2048; tt += 1024) {
    int ln = tt & 63, fr = tt >> 6;
    int mat = fr >> 4, kt = (fr >> 2) & 3, nt = fr & 3;
    int o = (ln & 15) + 16 * nt;
    int k0 = 8 * (ln >> 4) + 32 * kt;
    uint wbits[4];
#pragma unroll
    for (int jj = 0; jj < 4; ++jj) {
      float vv[2];
#pragma unroll
      for (int s = 0; s < 2; ++s) {
        int k = k0 + 2 * jj + s;
        float2 wrwi = h2_to_f2(sWh[(k & 63) * 64 + o]);
        vv[s] = (k < 64) ? wrwi.x : (mat ? wrwi.y : -wrwi.y);
      }
      __half2 hh = __floats2half2_rn(vv[0], vv[1]);
      wbits[jj] = *(uint*)&hh;
    }
    Bfrag[tt] = make_uint4(wbits[0], wbits[1], wbits[2], wbits[3]);
  }
}

// ---------- partition: direct scatter into fixed slots ----------
// Each block counts its chunk (int4 loads, LDS histogram), reserves a range
// per bucket via ONE strided global atomicAdd, then scatters.
// pack = (node_local<<17) | neighbor.
__global__ __launch_bounds__(256) void part_scatter(
    const int* __restrict__ row, const int* __restrict__ col,
    int* __restrict__ Ccur,
    uint* __restrict__ pout, uint* __restrict__ pin, int E, int NBUK, int CH) {
  __shared__ int co[256], ci[256];
  int t = threadIdx.x, g = blockIdx.x;
  co[t] = 0;
  ci[t] = 0;
  __syncthreads();
  int e0 = g * CH, e1 = min(E, e0 + CH);
  int g0 = e0 >> 2, g1 = (e1 + 3) >> 2;  // CH%4==0 -> exact int4 groups
  for (int gi = g0 + t; gi < g1; gi += 256) {
    int4 r4 = ((const int4*)row)[gi];
    int4 c4 = ((const int4*)col)[gi];
    atomicAdd(&co[r4.x >> 9], 1);
    atomicAdd(&co[r4.y >> 9], 1);
    atomicAdd(&co[r4.z >> 9], 1);
    atomicAdd(&co[r4.w >> 9], 1);
    atomicAdd(&ci[c4.x >> 9], 1);
    atomicAdd(&ci[c4.y >> 9], 1);
    atomicAdd(&ci[c4.z >> 9], 1);
    atomicAdd(&ci[c4.w >> 9], 1);
  }
  __syncthreads();
  if (t < NBUK) {
    int c = co[t];
    co[t] = c ? atomicAdd(&Ccur[t << 4], c) : 0;
    c = ci[t];
    ci[t] = c ? atomicAdd(&Ccur[(NBUK + t) << 4], c) : 0;
  }
  __syncthreads();
  for (int gi = g0 + t; gi < g1; gi += 256) {
    int4 r4 = ((const int4*)row)[gi];
    int4 c4 = ((const int4*)col)[gi];
#define SCAT1(R, C)                                          \
  {                                                          \
    int po = atomicAdd(&co[(R) >> 9], 1);                    \
    pout[po] = ((uint)((R) & 511) << 17) | (uint)(C);        \
    int pi = atomicAdd(&ci[(C) >> 9], 1);                    \
    pin[pi] = ((uint)((C) & 511) << 17) | (uint)(R);         \
  }
    SCAT1(r4.x, c4.x);
    SCAT1(r4.y, c4.y);
    SCAT1(r4.z, c4.z);
    SCAT1(r4.w, c4.w);
#undef SCAT1
  }
}

// One block per (bucket,dir): LDS degree histogram (4-way unrolled) + LOCAL
// 512-element exclusive scan -> per-node int2 range {start, end} inside the
// bucket's idx slot, and inv = deg^-0.25. cnt comes from the final cursor.
__global__ __launch_bounds__(256) void offsets_kernel(
    const uint* __restrict__ pout, const uint* __restrict__ pin,
    const int* __restrict__ Ccur,
    int2* __restrict__ ofsp_out, int2* __restrict__ ofsp_in,
    float* __restrict__ inv_out, float* __restrict__ inv_in,
    int NBUK, int N) {
  const uint* p = blockIdx.y ? pin : pout;
  int2* ofsp = blockIdx.y ? ofsp_in : ofsp_out;
  float* inv = blockIdx.y ? inv_in : inv_out;
  __shared__ int ld[512];
  __shared__ int ws[4];
  int t = threadIdx.x, b = blockIdx.x;
  ld[t] = 0;
  ld[t + 256] = 0;
  __syncthreads();
  int win_s = b * SLOTSZ;
  int win_e = Ccur[((blockIdx.y ? NBUK : 0) + b) << 4];  // final cursor
  int j = win_s + t;
  for (; j + 768 < win_e; j += 1024) {
    uint p0 = p[j], p1 = p[j + 256], p2 = p[j + 512], p3 = p[j + 768];
    atomicAdd(&ld[p0 >> 17], 1);
    atomicAdd(&ld[p1 >> 17], 1);
    atomicAdd(&ld[p2 >> 17], 1);
    atomicAdd(&ld[p3 >> 17], 1);
  }
  for (; j < win_e; j += 256) atomicAdd(&ld[p[j] >> 17], 1);
  __syncthreads();
  int a0 = ld[2 * t], a1 = ld[2 * t + 1], sm = a0 + a1;
  int lane = t & 63, wv = t >> 6, sc = sm;
#pragma unroll
  for (int off = 1; off < 64; off <<= 1) {
    int u = __shfl_up(sc, off);
    if (lane >= off) sc += u;
  }
  if (lane == 63) ws[wv] = sc;
  __syncthreads();
  int wbase = 0;
#pragma unroll
  for (int w = 0; w < 4; ++w)
    if (w < wv) wbase += ws[w];
  int excl = wbase + sc - sm;
  int n0 = (b << 9) + 2 * t;
  int st0 = win_s + excl;
  if (n0 < N) {
    ofsp[n0] = make_int2(st0, st0 + a0);
    inv[n0] = a0 ? rsqrtf(sqrtf((float)a0)) : 0.0f;
  }
  if (n0 + 1 < N) {
    ofsp[n0 + 1] = make_int2(st0 + a0, st0 + a0 + a1);
    inv[n0 + 1] = a1 ? rsqrtf(sqrtf((float)a1)) : 0.0f;
  }
}

// One block per (bucket,dir): LDS cursors seeded from ofsp; 4-way unrolled
// fill. idx entry = (f16bits(inv_of_neighbor)<<17) | neighbor. y=0: pout ->
// idx_out, neighbors are cols -> inv_in; y=1: pin -> idx_in -> inv_out.
// (Separate dispatch: the inv gather needs ALL inv values finished.)
__global__ __launch_bounds__(256) void bucket_fill(
    const uint* __restrict__ pout, const uint* __restrict__ pin,
    const int* __restrict__ Ccur,
    const int2* __restrict__ ofsp_out, const int2* __restrict__ ofsp_in,
    const float* __restrict__ inv_out, const float* __restrict__ inv_in,
    uint* __restrict__ idx_out, uint* __restrict__ idx_in, int NBUK, int N) {
  const uint* p = blockIdx.y ? pin : pout;
  const int2* ofsp = blockIdx.y ? ofsp_in : ofsp_out;
  const float* invnb = blockIdx.y ? inv_out : inv_in;
  uint* idx = blockIdx.y ? idx_in : idx_out;
  __shared__ int cur[512];
  int t = threadIdx.x, b = blockIdx.x;
  int n0 = (b << 9) + t;
  cur[t] = (n0 < N) ? ofsp[n0].x : 0;
  cur[t + 256] = (n0 + 256 < N) ? ofsp[n0 + 256].x : 0;
  __syncthreads();
  int s = b * SLOTSZ;
  int e = Ccur[((blockIdx.y ? NBUK : 0) + b) << 4];
#define FILL1(PK)                                                       \
  {                                                                     \
    uint nbr = (PK) & 0x1FFFFu;                                         \
    uint hb = (uint)__half_as_ushort(__float2half(invnb[nbr]));         \
    int pos = atomicAdd(&cur[(PK) >> 17], 1);                           \
    idx[pos] = (hb << 17) | nbr;                                        \
  }
  int j = s + t;
  for (; j + 768 < e; j += 1024) {
    uint p0 = p[j], p1 = p[j + 256], p2 = p[j + 512], p3 = p[j + 768];
    FILL1(p0);
    FILL1(p1);
    FILL1(p2);
    FILL1(p3);
  }
  for (; j < e; j += 256) {
    uint pk = p[j];
    FILL1(pk);
  }
#undef FILL1
}

// ---------- dense prep ----------

// Unscaled packed features: xp[n*64+d] = half2(xr, xi). 25.6 MB, single array
// for both gather directions (scale rides in the idx entries).
__global__ void pack_kernel(const float* __restrict__ xr, const float* __restrict__ xi,
                            uint* __restrict__ xp, int total4) {
  int i = blockIdx.x * blockDim.x + threadIdx.x;  // over N*16 uint4 groups
  if (i < total4) {
    float4 a = ((const float4*)xr)[i];
    float4 b = ((const float4*)xi)[i];
    __half2 h;
    uint4 o;
    h = __floats2half2_rn(a.x, b.x); o.x = *(uint*)&h;
    h = __floats2half2_rn(a.y, b.y); o.y = *(uint*)&h;
    h = __floats2half2_rn(a.z, b.z); o.z = *(uint*)&h;
    h = __floats2half2_rn(a.w, b.w); o.w = *(uint*)&h;
    ((uint4*)xp)[i] = o;
  }
}

// ---------- sparse gather (R8 form; ranges via int2) ----------
// One wave per node. Lane l handles features 4*(l&15)..+3 of edge j+(l>>4):
// one dwordx4 gather covers 4 edges per wave-instruction; unroll 2.
// idx entry = (f16bits(inv_nbr)<<17)|nbr; accumulate via fma with decoded scale.
// Output: Apack[n][k], k in [0,192) f16: [p(64) | sh(64) | u(64)], written by
// the sub==0 quarter-wave. No LDS (epilogue lives in gemm_kernel).
__global__ __launch_bounds__(256) void gather_kernel(
    const uint4* __restrict__ xp4,
    const uint* __restrict__ idx_out, const uint* __restrict__ idx_in,
    const int2* __restrict__ ofsp_out, const int2* __restrict__ ofsp_in,
    const float* __restrict__ inv_out, const float* __restrict__ inv_in,
    uint* __restrict__ Apack, int N) {
  int wv = threadIdx.x >> 6;
  int lane = threadIdx.x & 63;
  int sub = lane >> 4;  // edge slot 0..3
  int q = lane & 15;    // uint4 slot -> features 4q..4q+3
  int wid = blockIdx.x * 4 + wv;
  int nw = gridDim.x * 4;
  for (int n = wid; n < N; n += nw) {
    float4 u1 = {0, 0, 0, 0}, s1 = {0, 0, 0, 0};
    float4 v2 = {0, 0, 0, 0}, s2 = {0, 0, 0, 0};
#define ACC(P, SC, U, S)                                                \
  {                                                                     \
    float2 a0 = h2_to_f2((P).x), a1 = h2_to_f2((P).y);                  \
    float2 a2 = h2_to_f2((P).z), a3 = h2_to_f2((P).w);                  \
    U.x += SC * a0.x; S.x += SC * a0.y; U.y += SC * a1.x; S.y += SC * a1.y; \
    U.z += SC * a2.x; S.z += SC * a2.y; U.w += SC * a3.x; S.w += SC * a3.y; \
  }
#define DEC(E) __half2float(__ushort_as_half((ushort)((E) >> 17)))
    {  // out-direction: neighbors scaled by inv_in[nbr] (in idx bits)
      int2 se = ofsp_out[n];
      int lo = se.x, hi = se.y;
      int len8 = (hi - lo) & ~7;
      int j = lo;
      for (; j < lo + len8; j += 8) {
        uint e0 = idx_out[j + sub];
        uint e1 = idx_out[j + 4 + sub];
        uint4 p0 = xp4[(size_t)(e0 & 0x1FFFFu) * 16 + q];
        uint4 p1 = xp4[(size_t)(e1 & 0x1FFFFu) * 16 + q];
        float sc0 = DEC(e0), sc1 = DEC(e1);
        ACC(p0, sc0, u1, s1);
        ACC(p1, sc1, u1, s1);
      }
      for (; j < hi; j += 4) {
        if (j + sub < hi) {
          uint e0 = idx_out[j + sub];
          uint4 p0 = xp4[(size_t)(e0 & 0x1FFFFu) * 16 + q];
          float sc0 = DEC(e0);
          ACC(p0, sc0, u1, s1);
        }
      }
    }
    {  // in-direction: neighbors scaled by inv_out[nbr] (in idx bits)
      int2 se = ofsp_in[n];
      int lo = se.x, hi = se.y;
      int len8 = (hi - lo) & ~7;
      int j = lo;
      for (; j < lo + len8; j += 8) {
        uint e0 = idx_in[j + sub];
        uint e1 = idx_in[j + 4 + sub];
        uint4 p0 = xp4[(size_t)(e0 & 0x1FFFFu) * 16 + q];
        uint4 p1 = xp4[(size_t)(e1 & 0x1FFFFu) * 16 + q];
        float sc0 = DEC(e0), sc1 = DEC(e1);
        ACC(p0, sc0, v2, s2);
        ACC(p1, sc1, v2, s2);
      }
      for (; j < hi; j += 4) {
        if (j + sub < hi) {
          uint e0 = idx_in[j + sub];
          uint4 p0 = xp4[(size_t)(e0 & 0x1FFFFu) * 16 + q];
          float sc0 = DEC(e0);
          ACC(p0, sc0, v2, s2);
        }
      }
    }
#undef ACC
#undef DEC
    // reduce the 4 edge-subgroups (lanes l, l^16, l^32, l^48)
#pragma unroll
    for (int m = 16; m < 64; m <<= 1) {
      u1.x += __shfl_xor(u1.x, m); u1.y += __shfl_xor(u1.y, m);
      u1.z += __shfl_xor(u1.z, m); u1.w += __shfl_xor(u1.w, m);
      s1.x += __shfl_xor(s1.x, m); s1.y += __shfl_xor(s1.y, m);
      s1.z += __shfl_xor(s1.z, m); s1.w += __shfl_xor(s1.w, m);
      v2.x += __shfl_xor(v2.x, m); v2.y += __shfl_xor(v2.y, m);
      v2.z += __shfl_xor(v2.z, m); v2.w += __shfl_xor(v2.w, m);
      s2.x += __shfl_xor(s2.x, m); s2.y += __shfl_xor(s2.y, m);
      s2.z += __shfl_xor(s2.z, m); s2.w += __shfl_xor(s2.w, m);
    }
    if (sub == 0) {  // lanes 0..15 hold features 4q..4q+3
      float io = inv_out[n], ii = inv_in[n];
      float4 uu = make_float4(io * u1.x, io * u1.y, io * u1.z, io * u1.w);
      float4 vv = make_float4(ii * v2.x, ii * v2.y, ii * v2.z, ii * v2.w);
      float4 ss = make_float4(io * s1.x + ii * s2.x, io * s1.y + ii * s2.y,
                              io * s1.z + ii * s2.z, io * s1.w + ii * s2.w);
      uint* base = Apack + (size_t)n * 96 + 2 * q;  // row = 192 f16 = 96 uints
      __half2 h;
      uint2 w;
      h = __floats2half2_rn(0.5f * (uu.x + vv.x), 0.5f * (uu.y + vv.y)); w.x = *(uint*)&h;
      h = __floats2half2_rn(0.5f * (uu.z + vv.z), 0.5f * (uu.w + vv.w)); w.y = *(uint*)&h;
      *(uint2*)base = w;  // p
      h = __floats2half2_rn(0.5f * ss.x, 0.5f * ss.y); w.x = *(uint*)&h;
      h = __floats2half2_rn(0.5f * ss.z, 0.5f * ss.w); w.y = *(uint*)&h;
      *(uint2*)(base + 32) = w;  // sh
      h = __floats2half2_rn(uu.x, uu.y); w.x = *(uint*)&h;
      h = __floats2half2_rn(uu.z, uu.w); w.y = *(uint*)&h;
      *(uint2*)(base + 64) = w;  // u
    }
  }
}

// ---------- dense epilogue: tall-skinny MFMA GEMM (R8 form, verbatim) ----------
// Per wave per 16-node tile: 6 A-frags (k windows of 32), 32 mfma_f32_16x16x32_f16.
//   real: C[n][o]   = sum_{kt=0..3} A(kt)   * Breal(kt)   (k in [0,128))
//   imag: C[n][o]   = sum_{kt=0..3} A(kt+2) * Bimag(kt)   (k in [64,192))
// A-frag: row = lane&15, k = 8*(lane>>4)+j. B-frag: col = lane&15, same k.
// C/D: col = lane&15, row = 4*(lane>>4)+reg  [m89-verified layout].
__global__ __launch_bounds__(256) void gemm_kernel(
    const ushort* __restrict__ Apack, const uint4* __restrict__ Bfrag,
    const float* __restrict__ cR, const float* __restrict__ cI,
    float* __restrict__ out_real, float* __restrict__ out_imag, int N) {
  __shared__ uint4 sB[2048];  // 32 KB: [fr(32)][lane(64)]
  for (int i = threadIdx.x; i < 2048; i += 256) sB[i] = Bfrag[i];
  __syncthreads();
  int lane = threadIdx.x & 63, wv = threadIdx.x >> 6;
  int l15 = lane & 15, l4 = lane >> 4;
  float bR[4], bI[4];
#pragma unroll
  for (int nt = 0; nt < 4; ++nt) {
    bR[nt] = cR[l15 + 16 * nt];
    bI[nt] = cI[l15 + 16 * nt];
  }
  int tiles = (N + 15) >> 4;
  int gw = blockIdx.x * 4 + wv, nw = gridDim.x * 4;
  for (int tt = gw; tt < tiles; tt += nw) {
    int n0 = tt << 4;
    int arow = min(n0 + l15, N - 1);
    const ushort* ap = Apack + (size_t)arow * 192 + 8 * l4;
    f16x8 a[6];
#pragma unroll
    for (int kt = 0; kt < 6; ++kt) a[kt] = *(const f16x8*)(ap + 32 * kt);
    f32x4 cr[4], ci[4];
#pragma unroll
    for (int nt = 0; nt < 4; ++nt) {
      cr[nt] = (f32x4){0.f, 0.f, 0.f, 0.f};
      ci[nt] = (f32x4){0.f, 0.f, 0.f, 0.f};
    }
#pragma unroll
    for (int kt = 0; kt < 4; ++kt) {
#pragma unroll
      for (int nt = 0; nt < 4; ++nt) {
        f16x8 b0 = *(const f16x8*)&sB[(kt * 4 + nt) * 64 + lane];
        cr[nt] = __builtin_amdgcn_mfma_f32_16x16x32_f16(a[kt], b0, cr[nt], 0, 0, 0);
        f16x8 b1 = *(const f16x8*)&sB[(16 + kt * 4 + nt) * 64 + lane];
        ci[nt] = __builtin_amdgcn_mfma_f32_16x16x32_f16(a[kt + 2], b1, ci[nt], 0, 0, 0);
      }
    }
#pragma unroll
    for (int nt = 0; nt < 4; ++nt) {
#pragma unroll
      for (int r = 0; r < 4; ++r) {
        int node = n0 + 4 * l4 + r;
        if (node < N) {
          out_real[(size_t)node * 64 + l15 + 16 * nt] = cr[nt][r] + bR[nt];
          out_imag[(size_t)node * 64 + l15 + 16 * nt] = ci[nt][r] + bI[nt];
        }
      }
    }
  }
}

extern "C" void kernel_launch(void* const* d_in, const int* in_sizes, int n_in,
                              void* d_out, int out_size, void* d_ws, size_t ws_size,
                              hipStream_t stream) {
  const float* x_real = (const float*)d_in[0];
  const float* x_imag = (const float*)d_in[1];
  const int* edge = (const int*)d_in[2];
  const float* W_real = (const float*)d_in[3];
  const float* b_real = (const float*)d_in[4];
  const float* W_imag = (const float*)d_in[5];
  const float* b_imag = (const float*)d_in[6];

  const int N = in_sizes[0] / D;  // 100000
  const int E = in_sizes[2] / 2;  // 1600000
  const int* row = edge;
  const int* col = edge + E;

  const int NBUK = (N + 511) >> 9;            // 196 buckets of 512 nodes
  const int CH = ((E / GSC + 3) & ~3);        // edges per scatter block (mult of 4)
  const size_t SLOTS = (size_t)NBUK * SLOTSZ; // 3.21M entries per (array,dir)

  // workspace layout (16B-aligned packed arrays first).
  // pout/pin (2*SLOTS = 25.7 MB) alias Apack (N*96 = 38.4 MB): they die after
  // bucket_fill; Apack is written by gather_kernel afterwards.
  uint* xp       = (uint*)d_ws;                    // N*64 (unscaled half2 pack)
  uint* idx_out  = xp + (size_t)N * D;             // SLOTS (slot-padded)
  uint* idx_in   = idx_out + SLOTS;                // SLOTS
  uint* Apack    = idx_in + SLOTS;                 // N*96  (f16 [N][192])
  uint* pout     = Apack;                          // SLOTS (aliased, dead early)
  uint* pin      = pout + SLOTS;                   // SLOTS (aliased, dead early)
  uint4* Bfrag   = (uint4*)(Apack + (size_t)N * 96);  // 2048 uint4 = 32 KB
  int* Ccur      = (int*)(Bfrag + 2048);           // 2*NBUK*16 (strided cursors)
  int2* ofsp_out = (int2*)(Ccur + 2 * NBUK * 16);  // N (start,end)
  int2* ofsp_in  = ofsp_out + N;                   // N
  float* inv_out = (float*)(ofsp_in + N);          // N
  float* inv_in  = inv_out + N;                    // N
  float* cR      = inv_in + N;                     // 64
  float* cI      = cR + 64;                        // 64

  float* out_real = (float*)d_out;
  float* out_imag = out_real + (size_t)N * D;

  // weights + B-fragments + cursor seed (no count pass, no memset)
  prep_kernel<<<1, 1024, 0, stream>>>(W_real, b_real, W_imag, b_imag,
                                      Bfrag, cR, cI, Ccur, NBUK);

  // unscaled feature pack (independent of the edge chain)
  pack_kernel<<<(N * 16 + 255) / 256, 256, 0, stream>>>(x_real, x_imag, xp, N * 16);

  // scatter edges directly into fixed bucket slots (atomic range reservation)
  part_scatter<<<GSC, 256, 0, stream>>>(row, col, Ccur, pout, pin, E, NBUK, CH);

  // per-bucket degrees -> int2 ranges + inv via local scan
  offsets_kernel<<<dim3(NBUK, 2), 256, 0, stream>>>(pout, pin, Ccur,
                                                    ofsp_out, ofsp_in,
                                                    inv_out, inv_in, NBUK, N);

  // per-bucket CSR fill (block-private windows; packs inv scale into idx)
  bucket_fill<<<dim3(NBUK, 2), 256, 0, stream>>>(pout, pin, Ccur,
                                                 ofsp_out, ofsp_in,
                                                 inv_out, inv_in,
                                                 idx_out, idx_in, NBUK, N);

  // sparse gather -> Apack (overwrites pout/pin, now dead)
  gather_kernel<<<4096, 256, 0, stream>>>((const uint4*)xp, idx_out, idx_in,
                                          ofsp_out, ofsp_in, inv_out, inv_in,
                                          Apack, N);
  // dense epilogue: MFMA GEMM
  gemm_kernel<<<1568, 256, 0, stream>>>((const ushort*)Apack, Bfrag, cR, cI,
                                        out_real, out_imag, N);
}